// Round 7
// baseline (7983.355 us; speedup 1.0000x reference)
//
#include <hip/hip_runtime.h>

#define T_LEN 1024
#define BATCH 256
#define HID   30
#define GATES 120

__device__ __forceinline__ float fsigmoid(float x) {
    return 1.0f / (1.0f + __expf(-x));
}
__device__ __forceinline__ float ftanh(float x) {
    x = fminf(fmaxf(x, -15.0f), 15.0f);
    float e = __expf(2.0f * x);
    return (e - 1.0f) / (e + 1.0f);
}

// One block per (batch element, direction). 128 threads; threads 0..119 each
// own one gate row (weights in registers), threads 0..29 also own c[j]/h[j].
// h broadcast via LDS; x double-buffered in LDS with 1-step prefetch.
template<int IN_L>
__global__ __launch_bounds__(128)
void lstm_layer(const float* __restrict__ in, int in_stride,
                float* __restrict__ out,
                const float* __restrict__ wih,   // [2, 120, IN_L] (pre-offset to layer)
                const float* __restrict__ whh,   // [2, 120, 30]
                const float* __restrict__ bias,  // [2, 120]
                const float* __restrict__ h0,    // [2, B, 30]
                const float* __restrict__ c0)    // [2, B, 30]
{
    const int b   = blockIdx.x;
    const int d   = blockIdx.y;
    const int tid = threadIdx.x;

    __shared__ float xs[2][(IN_L > 32) ? 64 : 32];
    __shared__ float hs[HID];
    __shared__ float act[GATES];

    float w[IN_L + HID];
    float bb = 0.0f, c = 0.0f;

    if (tid < GATES) {
        const float* wr = wih + (size_t)(d * GATES + tid) * IN_L;
        #pragma unroll
        for (int k = 0; k < IN_L; k++) w[k] = wr[k];
        const float* hr = whh + (size_t)(d * GATES + tid) * HID;
        #pragma unroll
        for (int k = 0; k < HID; k++) w[IN_L + k] = hr[k];
        bb = bias[d * GATES + tid];
    }
    if (tid < HID) {
        hs[tid] = h0[((size_t)d * BATCH + b) * HID + tid];
        c       = c0[((size_t)d * BATCH + b) * HID + tid];
    }

    const int t0 = (d == 0) ? 0 : (T_LEN - 1);
    const int ts = (d == 0) ? 1 : -1;
    const float* xin  = in  + (size_t)b * T_LEN * in_stride;
    float*       outb = out + (size_t)b * T_LEN * 60 + d * HID;

    if (tid < IN_L) xs[0][tid] = xin[(size_t)t0 * in_stride + tid];
    __syncthreads();

    for (int i = 0; i < T_LEN; i++) {
        const int t = t0 + i * ts;
        // prefetch next timestep's input slice
        float xn = 0.0f;
        if (i + 1 < T_LEN && tid < IN_L)
            xn = xin[(size_t)(t + ts) * in_stride + tid];
        const int cur = i & 1;

        if (tid < GATES) {
            float a0 = bb, a1 = 0.f, a2 = 0.f, a3 = 0.f;
            constexpr int KI = IN_L & ~3;
            #pragma unroll
            for (int k = 0; k < KI; k += 4) {
                a0 += w[k + 0] * xs[cur][k + 0];
                a1 += w[k + 1] * xs[cur][k + 1];
                a2 += w[k + 2] * xs[cur][k + 2];
                a3 += w[k + 3] * xs[cur][k + 3];
            }
            #pragma unroll
            for (int k = KI; k < IN_L; k++) a0 += w[k] * xs[cur][k];
            #pragma unroll
            for (int k = 0; k < 28; k += 4) {
                a0 += w[IN_L + k + 0] * hs[k + 0];
                a1 += w[IN_L + k + 1] * hs[k + 1];
                a2 += w[IN_L + k + 2] * hs[k + 2];
                a3 += w[IN_L + k + 3] * hs[k + 3];
            }
            a0 += w[IN_L + 28] * hs[28];
            a1 += w[IN_L + 29] * hs[29];
            float acc = (a0 + a1) + (a2 + a3);
            // gate order: i(0..29), f(30..59), g(60..89), o(90..119)
            act[tid] = (tid >= 60 && tid < 90) ? ftanh(acc) : fsigmoid(acc);
        }
        if (i + 1 < T_LEN && tid < IN_L) xs[cur ^ 1][tid] = xn;
        __syncthreads();

        if (tid < HID) {
            c = act[HID + tid] * c + act[tid] * act[60 + tid];
            float hn = act[90 + tid] * ftanh(c);
            hs[tid] = hn;
            outb[(size_t)t * 60 + tid] = hn;
        }
        __syncthreads();
    }
}

__global__ void fc_kernel(const float* __restrict__ hbuf,  // [B, T, 60]
                          const float* __restrict__ fc_w,  // [2, 60]
                          const float* __restrict__ fc_b,  // [2]
                          float* __restrict__ out)         // [B, 2]
{
    int b = threadIdx.x;
    if (b < BATCH) {
        const float* h = hbuf + ((size_t)b * T_LEN + (T_LEN - 1)) * 60;
        #pragma unroll
        for (int j = 0; j < 2; j++) {
            float acc = fc_b[j];
            #pragma unroll
            for (int k = 0; k < 60; k++) acc += fc_w[j * 60 + k] * h[k];
            out[b * 2 + j] = ftanh(acc);
        }
    }
}

extern "C" void kernel_launch(void* const* d_in, const int* in_sizes, int n_in,
                              void* d_out, int out_size, void* d_ws, size_t ws_size,
                              hipStream_t stream) {
    const float* x          = (const float*)d_in[0];
    const float* w_ih1_l0   = (const float*)d_in[1];
    const float* w_ih1_rest = (const float*)d_in[2];
    const float* w_hh1      = (const float*)d_in[3];
    const float* b1         = (const float*)d_in[4];
    const float* w_ih2      = (const float*)d_in[5];
    const float* w_hh2      = (const float*)d_in[6];
    const float* b2         = (const float*)d_in[7];
    const float* h01        = (const float*)d_in[8];
    const float* c01        = (const float*)d_in[9];
    const float* h02        = (const float*)d_in[10];
    const float* c02        = (const float*)d_in[11];
    const float* fc_w       = (const float*)d_in[12];
    const float* fc_b       = (const float*)d_in[13];
    float* out = (float*)d_out;

    float* bufA = (float*)d_ws;
    float* bufB = bufA + (size_t)BATCH * T_LEN * 60;

    dim3 grid(BATCH, 2), blk(128);

    // ---- stack 1 ----
    lstm_layer<21><<<grid, blk, 0, stream>>>(x, 21, bufA,
        w_ih1_l0, w_hh1, b1, h01, c01);
    const float* curb = bufA;
    float*       nxtb = bufB;
    for (int l = 1; l < 5; l++) {
        lstm_layer<60><<<grid, blk, 0, stream>>>(curb, 60, nxtb,
            w_ih1_rest + (size_t)(l - 1) * 2 * GATES * 60,
            w_hh1      + (size_t)l * 2 * GATES * HID,
            b1         + (size_t)l * 2 * GATES,
            h01        + (size_t)l * 2 * BATCH * HID,
            c01        + (size_t)l * 2 * BATCH * HID);
        float* tmp = (float*)curb; curb = nxtb; nxtb = tmp;
    }
    // ---- stack 2 ----
    for (int l = 0; l < 5; l++) {
        lstm_layer<60><<<grid, blk, 0, stream>>>(curb, 60, nxtb,
            w_ih2 + (size_t)l * 2 * GATES * 60,
            w_hh2 + (size_t)l * 2 * GATES * HID,
            b2    + (size_t)l * 2 * GATES,
            h02   + (size_t)l * 2 * BATCH * HID,
            c02   + (size_t)l * 2 * BATCH * HID);
        float* tmp = (float*)curb; curb = nxtb; nxtb = tmp;
    }

    fc_kernel<<<1, 256, 0, stream>>>(curb, fc_w, fc_b, out);
}

// Round 10
// 5994.199 us; speedup vs baseline: 1.3318x; 1.3318x over previous
//
#include <hip/hip_runtime.h>

#define T_LEN 1024
#define BATCH 256
#define HID   30

__device__ __forceinline__ float ftanh(float x) {
    x = fminf(fmaxf(x, -15.0f), 15.0f);
    float e = __expf(2.0f * x);
    return (e - 1.0f) / (e + 1.0f);
}

__device__ __forceinline__ float rl(float v, int srclane) {
    return __int_as_float(__builtin_amdgcn_readlane(__float_as_int(v), srclane));
}

// Single-wave LSTM layer: one 64-thread block per (batch, dir).
// Lane j<30 owns gates i_j (slot A) and g_j (slot B); lane j+30 owns f_j (A)
// and o_j (B). Weights live in VGPRs. h broadcast via v_readlane (register,
// no sync); f/o fetched with __shfl; x broadcast via LDS tiles staged every
// 16 steps with explicit lgkmcnt fences. ZERO barriers -> no vmcnt drains:
// h-stores are fire-and-forget, x prefetch latency amortized over 16 steps.
template<int IN_L>
__global__ __launch_bounds__(64, 1)
void lstm_wave(const float* __restrict__ in,
               float* __restrict__ out,
               const float* __restrict__ wih,   // [2,120,IN_L] pre-offset to layer
               const float* __restrict__ whh,   // [2,120,30]
               const float* __restrict__ bias,  // [2,120]
               const float* __restrict__ h0,    // [2,B,30]
               const float* __restrict__ c0)    // [2,B,30]
{
    constexpr int WS    = 16;            // steps per staged window
    constexpr int NW    = T_LEN / WS;    // 64 windows
    constexpr int ELEMS = WS * IN_L;     // floats per window
    constexpr int NLOAD = (ELEMS + 63) / 64;

    const int b = blockIdx.x, d = blockIdx.y, lane = threadIdx.x;

    __shared__ float xt[2][ELEMS];

    // ---- weights into registers (2 gate rows per lane) ----
    float wA[IN_L + HID], wB[IN_L + HID];
    float bA = 0.f, bB = 0.f;
    if (lane < 60) {
        const float* ra = wih + (size_t)(d * 120 + lane) * IN_L;
        const float* rb = ra + 60 * IN_L;
        #pragma unroll
        for (int k = 0; k < IN_L; k++) { wA[k] = ra[k]; wB[k] = rb[k]; }
        const float* ha = whh + (size_t)(d * 120 + lane) * HID;
        const float* hb = ha + 60 * HID;
        #pragma unroll
        for (int k = 0; k < HID; k++) { wA[IN_L + k] = ha[k]; wB[IN_L + k] = hb[k]; }
        bA = bias[d * 120 + lane];
        bB = bias[d * 120 + 60 + lane];
    }

    // ---- initial h (lanes 0..29 hold h_j) and c ----
    float hval = 0.f, cval = 0.f;
    {
        int j = (lane < HID) ? lane : 0;
        float hl = h0[(size_t)(d * BATCH + b) * HID + j];
        float cl = c0[(size_t)(d * BATCH + b) * HID + j];
        if (lane < HID) { hval = hl; cval = cl; }
    }

    const int t0 = d ? (T_LEN - 1) : 0;
    const int ts = d ? -1 : 1;
    const float* xin = in + (size_t)b * T_LEN * IN_L;
    float* outp = out + (size_t)b * T_LEN * 60 + (size_t)t0 * 60 + d * HID
                      + ((lane < HID) ? lane : 0);

    // per-lane window-invariant load offsets: element e=r*64+lane ->
    // (row delta ts*(e/IN_L), col e%IN_L) folded into one index
    int lofs[NLOAD];
    #pragma unroll
    for (int r = 0; r < NLOAD; r++) {
        int e = r * 64 + lane;
        lofs[r] = ts * (e / IN_L) * IN_L + (e % IN_L);
    }

    // activation constants: slot B is tanh for lanes<30 (g), sigmoid else (o)
    // via  actB = kba * sigmoid(km * a) + kbb
    const float km  = (lane < HID) ? 2.f : 1.f;
    const float kba = (lane < HID) ? 2.f : 1.f;
    const float kbb = (lane < HID) ? -1.f : 0.f;

    float xg[NLOAD];

    auto stage_load = [&](int w) {
        const float* base = xin + (size_t)(t0 + ts * (WS * w)) * IN_L;
        #pragma unroll
        for (int r = 0; r < NLOAD; r++) {
            int e = r * 64 + lane;
            if (e < ELEMS) xg[r] = base[lofs[r]];
        }
    };
    auto stage_write = [&](int buf) {
        // WAR: drain pending reads of this buffer from 2 windows ago
        asm volatile("s_waitcnt lgkmcnt(0)" ::: "memory");
        #pragma unroll
        for (int r = 0; r < NLOAD; r++) {
            int e = r * 64 + lane;
            if (e < ELEMS) xt[buf][e] = xg[r];
        }
        // RAW: writes visible before next window's broadcast reads
        asm volatile("s_waitcnt lgkmcnt(0)" ::: "memory");
        __builtin_amdgcn_sched_barrier(0);
    };

    stage_load(0);
    stage_write(0);

    for (int w = 0; w < NW; ++w) {
        if (w + 1 < NW) stage_load(w + 1);   // prefetch next window (16 steps to hide)
        const float* xb = xt[w & 1];
        #pragma unroll 2
        for (int s = 0; s < WS; ++s) {
            // ---- gate pre-activations: 4 independent FMA chains ----
            float aA0 = bA, aA1 = 0.f, aB0 = bB, aB1 = 0.f;
            const float* xr = xb + s * IN_L;
            #pragma unroll
            for (int k = 0; k + 1 < IN_L; k += 2) {
                float x0 = xr[k], x1 = xr[k + 1];      // uniform-addr LDS broadcast
                aA0 += wA[k] * x0;     aB0 += wB[k] * x0;
                aA1 += wA[k + 1] * x1; aB1 += wB[k + 1] * x1;
            }
            if constexpr (IN_L & 1) {
                float x0 = xr[IN_L - 1];
                aA0 += wA[IN_L - 1] * x0; aB0 += wB[IN_L - 1] * x0;
            }
            #pragma unroll
            for (int k = 0; k < HID; k += 2) {
                float h0v = rl(hval, k), h1v = rl(hval, k + 1);   // SGPR broadcast
                aA0 += wA[IN_L + k] * h0v;     aB0 += wB[IN_L + k] * h0v;
                aA1 += wA[IN_L + k + 1] * h1v; aB1 += wB[IN_L + k + 1] * h1v;
            }
            float aA = aA0 + aA1, aB = aB0 + aB1;

            // slot A: sigmoid (i for lanes<30, f for lanes 30..59)
            float sA = __builtin_amdgcn_rcpf(1.f + __expf(-aA));
            // slot B: tanh(g) lanes<30 / sigmoid(o) lanes 30..59, branch-free
            float sB = __builtin_amdgcn_rcpf(1.f + __expf(-(km * aB)));
            sB = kba * sB + kbb;

            // lane j<30 pulls sigmoid(f_j), sigmoid(o_j) from lane j+30
            float sf = __shfl(sA, lane + 30, 64);
            float so = __shfl(sB, lane + 30, 64);

            cval = sf * cval + sA * sB;                  // c' = f*c + i*tanh(g)
            float tc = 2.f * __builtin_amdgcn_rcpf(1.f + __expf(-2.f * cval)) - 1.f;
            float hn = so * tc;                          // h = o * tanh(c')
            hval = hn;                                   // lanes>=30: garbage, never read

            if (lane < HID) *outp = hn;                  // fire-and-forget, never drained
            outp += ts * 60;
        }
        if (w + 1 < NW) stage_write((w + 1) & 1);
    }
}

__global__ void fc_kernel(const float* __restrict__ hbuf,  // [B, T, 60]
                          const float* __restrict__ fc_w,  // [2, 60]
                          const float* __restrict__ fc_b,  // [2]
                          float* __restrict__ out)         // [B, 2]
{
    int b = threadIdx.x;
    if (b < BATCH) {
        const float* h = hbuf + ((size_t)b * T_LEN + (T_LEN - 1)) * 60;
        #pragma unroll
        for (int j = 0; j < 2; j++) {
            float acc = fc_b[j];
            #pragma unroll
            for (int k = 0; k < 60; k++) acc += fc_w[j * 60 + k] * h[k];
            out[b * 2 + j] = ftanh(acc);
        }
    }
}

extern "C" void kernel_launch(void* const* d_in, const int* in_sizes, int n_in,
                              void* d_out, int out_size, void* d_ws, size_t ws_size,
                              hipStream_t stream) {
    const float* x          = (const float*)d_in[0];
    const float* w_ih1_l0   = (const float*)d_in[1];
    const float* w_ih1_rest = (const float*)d_in[2];
    const float* w_hh1      = (const float*)d_in[3];
    const float* b1         = (const float*)d_in[4];
    const float* w_ih2      = (const float*)d_in[5];
    const float* w_hh2      = (const float*)d_in[6];
    const float* b2         = (const float*)d_in[7];
    const float* h01        = (const float*)d_in[8];
    const float* c01        = (const float*)d_in[9];
    const float* h02        = (const float*)d_in[10];
    const float* c02        = (const float*)d_in[11];
    const float* fc_w       = (const float*)d_in[12];
    const float* fc_b       = (const float*)d_in[13];
    float* out = (float*)d_out;

    float* bufA = (float*)d_ws;
    float* bufB = bufA + (size_t)BATCH * T_LEN * 60;

    dim3 grid(BATCH, 2), blk(64);

    // ---- stack 1 ----
    lstm_wave<21><<<grid, blk, 0, stream>>>(x, bufA,
        w_ih1_l0, w_hh1, b1, h01, c01);
    const float* curb = bufA;
    float*       nxtb = bufB;
    for (int l = 1; l < 5; l++) {
        lstm_wave<60><<<grid, blk, 0, stream>>>(curb, nxtb,
            w_ih1_rest + (size_t)(l - 1) * 2 * 120 * 60,
            w_hh1      + (size_t)l * 2 * 120 * HID,
            b1         + (size_t)l * 2 * 120,
            h01        + (size_t)l * 2 * BATCH * HID,
            c01        + (size_t)l * 2 * BATCH * HID);
        float* tmp = (float*)curb; curb = nxtb; nxtb = tmp;
    }
    // ---- stack 2 ----
    for (int l = 0; l < 5; l++) {
        lstm_wave<60><<<grid, blk, 0, stream>>>(curb, nxtb,
            w_ih2 + (size_t)l * 2 * 120 * 60,
            w_hh2 + (size_t)l * 2 * 120 * HID,
            b2    + (size_t)l * 2 * 120,
            h02   + (size_t)l * 2 * BATCH * HID,
            c02   + (size_t)l * 2 * BATCH * HID);
        float* tmp = (float*)curb; curb = nxtb; nxtb = tmp;
    }

    fc_kernel<<<1, 256, 0, stream>>>(curb, fc_w, fc_b, out);
}

// Round 13
// 5817.765 us; speedup vs baseline: 1.3722x; 1.0303x over previous
//
#include <hip/hip_runtime.h>

#define T_LEN 1024
#define BATCH 256
#define HID   30

__device__ __forceinline__ float ftanh(float x) {
    x = fminf(fmaxf(x, -15.0f), 15.0f);
    float e = __expf(2.0f * x);
    return (e - 1.0f) / (e + 1.0f);
}

__device__ __forceinline__ float rl(float v, int srclane) {
    return __int_as_float(__builtin_amdgcn_readlane(__float_as_int(v), srclane));
}

// Single-wave LSTM layer: one 64-thread block per (batch, dir).
// Lane j<30 owns gates i_j (slot A) and g_j (slot B); lane j+30 owns f_j (A)
// and o_j (B). Weights are PINNED in VGPRs via opaque asm (round-10 showed
// VGPR_Count=136 < 180 needed -> compiler was re-fetching weights per step).
// h broadcast via v_readlane; f/o via __shfl; x via LDS windows (WS=8) with
// explicit lgkmcnt fences. Zero barriers -> no vmcnt drains on the critical
// path; h-stores are fire-and-forget.
template<int IN_L>
__global__ __launch_bounds__(64, 1)
void lstm_wave(const float* __restrict__ in,
               float* __restrict__ out,
               const float* __restrict__ wih,   // [2,120,IN_L] pre-offset to layer
               const float* __restrict__ whh,   // [2,120,30]
               const float* __restrict__ bias,  // [2,120]
               const float* __restrict__ h0,    // [2,B,30]
               const float* __restrict__ c0)    // [2,B,30]
{
    constexpr int WS    = 8;             // steps per staged window (16->8: save regs)
    constexpr int NW    = T_LEN / WS;
    constexpr int ELEMS = WS * IN_L;
    constexpr int NLOAD = (ELEMS + 63) / 64;

    const int b = blockIdx.x, d = blockIdx.y, lane = threadIdx.x;

    __shared__ float xt[2][ELEMS];

    // ---- weights into registers (2 gate rows per lane, clamped row for 60..63) ----
    const int rowA = (lane < 60) ? lane : 59;
    float wA[IN_L + HID], wB[IN_L + HID];
    {
        const float* ra = wih + (size_t)(d * 120 + rowA) * IN_L;
        const float* rb = ra + 60 * IN_L;
        #pragma unroll
        for (int k = 0; k < IN_L; k++) { wA[k] = ra[k]; wB[k] = rb[k]; }
        const float* ha = whh + (size_t)(d * 120 + rowA) * HID;
        const float* hb = ha + 60 * HID;
        #pragma unroll
        for (int k = 0; k < HID; k++) { wA[IN_L + k] = ha[k]; wB[IN_L + k] = hb[k]; }
    }
    float bA = bias[d * 120 + rowA];
    float bB = bias[d * 120 + 60 + rowA];

    // PIN: opaque asm output -> compiler cannot rematerialize/sink these loads.
    #pragma unroll
    for (int k = 0; k < IN_L + HID; k++) {
        asm volatile("" : "+v"(wA[k]));
        asm volatile("" : "+v"(wB[k]));
    }
    asm volatile("" : "+v"(bA));
    asm volatile("" : "+v"(bB));

    // ---- initial h (lanes 0..29 hold h_j) and c ----
    float hval = 0.f, cval = 0.f;
    {
        int j = (lane < HID) ? lane : 0;
        float hl = h0[(size_t)(d * BATCH + b) * HID + j];
        float cl = c0[(size_t)(d * BATCH + b) * HID + j];
        if (lane < HID) { hval = hl; cval = cl; }
    }

    const int t0 = d ? (T_LEN - 1) : 0;
    const int ts = d ? -1 : 1;
    const float* xin = in + (size_t)b * T_LEN * IN_L;
    float* outp = out + (size_t)b * T_LEN * 60 + (size_t)t0 * 60 + d * HID
                      + ((lane < HID) ? lane : 0);

    // activation constants: slot B is tanh for lanes<30 (g), sigmoid else (o)
    const float km  = (lane < HID) ? 2.f : 1.f;
    const float kba = (lane < HID) ? 2.f : 1.f;
    const float kbb = (lane < HID) ? -1.f : 0.f;

    float xg[NLOAD];

    auto stage_load = [&](int w) {
        const float* base = xin + (size_t)(t0 + ts * (WS * w)) * IN_L;
        #pragma unroll
        for (int r = 0; r < NLOAD; r++) {
            int e = r * 64 + lane;
            if (e < ELEMS) xg[r] = base[ts * (e / IN_L) * IN_L + (e % IN_L)];
        }
    };
    auto stage_write = [&](int buf) {
        // WAR: drain pending LDS reads of this buffer before overwrite
        asm volatile("s_waitcnt lgkmcnt(0)" ::: "memory");
        #pragma unroll
        for (int r = 0; r < NLOAD; r++) {
            int e = r * 64 + lane;
            if (e < ELEMS) xt[buf][e] = xg[r];
        }
        // RAW: writes visible before next window's broadcast reads
        asm volatile("s_waitcnt lgkmcnt(0)" ::: "memory");
        __builtin_amdgcn_sched_barrier(0);
    };

    stage_load(0);
    stage_write(0);

    for (int w = 0; w < NW; ++w) {
        if (w + 1 < NW) stage_load(w + 1);   // prefetch next window (8 steps to hide)
        const float* xb = xt[w & 1];
        #pragma unroll 2
        for (int s = 0; s < WS; ++s) {
            // ---- gate pre-activations: 4 independent FMA chains ----
            float aA0 = bA, aA1 = 0.f, aB0 = bB, aB1 = 0.f;
            const float* xr = xb + s * IN_L;
            #pragma unroll
            for (int k = 0; k + 1 < IN_L; k += 2) {
                float x0 = xr[k], x1 = xr[k + 1];      // uniform-addr LDS broadcast
                aA0 += wA[k] * x0;     aB0 += wB[k] * x0;
                aA1 += wA[k + 1] * x1; aB1 += wB[k + 1] * x1;
            }
            if constexpr (IN_L & 1) {
                float x0 = xr[IN_L - 1];
                aA0 += wA[IN_L - 1] * x0; aB0 += wB[IN_L - 1] * x0;
            }
            #pragma unroll
            for (int k = 0; k < HID; k += 2) {
                float h0v = rl(hval, k), h1v = rl(hval, k + 1);   // SGPR broadcast
                aA0 += wA[IN_L + k] * h0v;     aB0 += wB[IN_L + k] * h0v;
                aA1 += wA[IN_L + k + 1] * h1v; aB1 += wB[IN_L + k + 1] * h1v;
            }
            float aA = aA0 + aA1, aB = aB0 + aB1;

            // slot A: sigmoid (i for lanes<30, f for lanes 30..59)
            float sA = __builtin_amdgcn_rcpf(1.f + __expf(-aA));
            // slot B: tanh(g) lanes<30 / sigmoid(o) lanes 30..59, branch-free
            float sB = __builtin_amdgcn_rcpf(1.f + __expf(-(km * aB)));
            sB = kba * sB + kbb;

            // lane j<30 pulls sigmoid(f_j), sigmoid(o_j) from lane j+30
            float sf = __shfl(sA, lane + 30, 64);
            float so = __shfl(sB, lane + 30, 64);

            cval = sf * cval + sA * sB;                  // c' = f*c + i*tanh(g)
            float tc = 2.f * __builtin_amdgcn_rcpf(1.f + __expf(-2.f * cval)) - 1.f;
            float hn = so * tc;                          // h = o * tanh(c')
            hval = hn;                                   // lanes>=30: garbage, never read

            if (lane < HID) *outp = hn;                  // fire-and-forget, never drained
            outp += ts * 60;
        }
        if (w + 1 < NW) stage_write((w + 1) & 1);
    }
}

__global__ void fc_kernel(const float* __restrict__ hbuf,  // [B, T, 60]
                          const float* __restrict__ fc_w,  // [2, 60]
                          const float* __restrict__ fc_b,  // [2]
                          float* __restrict__ out)         // [B, 2]
{
    int b = threadIdx.x;
    if (b < BATCH) {
        const float* h = hbuf + ((size_t)b * T_LEN + (T_LEN - 1)) * 60;
        #pragma unroll
        for (int j = 0; j < 2; j++) {
            float acc = fc_b[j];
            #pragma unroll
            for (int k = 0; k < 60; k++) acc += fc_w[j * 60 + k] * h[k];
            out[b * 2 + j] = ftanh(acc);
        }
    }
}

extern "C" void kernel_launch(void* const* d_in, const int* in_sizes, int n_in,
                              void* d_out, int out_size, void* d_ws, size_t ws_size,
                              hipStream_t stream) {
    const float* x          = (const float*)d_in[0];
    const float* w_ih1_l0   = (const float*)d_in[1];
    const float* w_ih1_rest = (const float*)d_in[2];
    const float* w_hh1      = (const float*)d_in[3];
    const float* b1         = (const float*)d_in[4];
    const float* w_ih2      = (const float*)d_in[5];
    const float* w_hh2      = (const float*)d_in[6];
    const float* b2         = (const float*)d_in[7];
    const float* h01        = (const float*)d_in[8];
    const float* c01        = (const float*)d_in[9];
    const float* h02        = (const float*)d_in[10];
    const float* c02        = (const float*)d_in[11];
    const float* fc_w       = (const float*)d_in[12];
    const float* fc_b       = (const float*)d_in[13];
    float* out = (float*)d_out;

    float* bufA = (float*)d_ws;
    float* bufB = bufA + (size_t)BATCH * T_LEN * 60;

    dim3 grid(BATCH, 2), blk(64);

    // ---- stack 1 ----
    lstm_wave<21><<<grid, blk, 0, stream>>>(x, bufA,
        w_ih1_l0, w_hh1, b1, h01, c01);
    const float* curb = bufA;
    float*       nxtb = bufB;
    for (int l = 1; l < 5; l++) {
        lstm_wave<60><<<grid, blk, 0, stream>>>(curb, nxtb,
            w_ih1_rest + (size_t)(l - 1) * 2 * 120 * 60,
            w_hh1      + (size_t)l * 2 * 120 * HID,
            b1         + (size_t)l * 2 * 120,
            h01        + (size_t)l * 2 * BATCH * HID,
            c01        + (size_t)l * 2 * BATCH * HID);
        float* tmp = (float*)curb; curb = nxtb; nxtb = tmp;
    }
    // ---- stack 2 ----
    for (int l = 0; l < 5; l++) {
        lstm_wave<60><<<grid, blk, 0, stream>>>(curb, nxtb,
            w_ih2 + (size_t)l * 2 * 120 * 60,
            w_hh2 + (size_t)l * 2 * 120 * HID,
            b2    + (size_t)l * 2 * 120,
            h02   + (size_t)l * 2 * BATCH * HID,
            c02   + (size_t)l * 2 * BATCH * HID);
        float* tmp = (float*)curb; curb = nxtb; nxtb = tmp;
    }

    fc_kernel<<<1, 256, 0, stream>>>(curb, fc_w, fc_b, out);
}